// Round 4
// baseline (306.948 us; speedup 1.0000x reference)
//
#include <hip/hip_runtime.h>

// YOLO loss: N=4096, S=14, B=2, NCLS=20. Cells = 802816.
// R4: compact-LDS element-parallel design. R3's 50KB LDS dropped residency to
// ~1 block/CU (occupancy 15%) and regressed 68->175us. Only the 10 box floats
// per cell need per-cell gather; cls loss is elementwise. So:
//  - threads walk the block's pred slab in coalesced float2 chunks (15/thread);
//    box-field chunks (pos<5) scatter to a 10KB LDS box array, cls-field
//    chunks difference against coalesced float2 tcls reads, weighted by
//    m[cell] from a 1KB LDS array.
//  - then thread t computes IoU/argmax/reg/contain for cell t from LDS.
// LDS ~= 11.4KB -> 8 blocks/CU (wave-capped), full latency hiding.
// Dispatches: (zero+detect), (main + fused last-block finalize).

#define NCELLS (4096 * 14 * 14)
#define TPB 256
#define NBLOCKS (NCELLS / TPB)  // 3136, exact

// ws layout (floats): [0..3] sums (cls,noobj,contain,reg); [4] block counter
// (uint); [8] mask-mode flag (int).

__global__ void yolo_init_kernel(float* ws, const unsigned char* mb) {
    if (threadIdx.x < 16) ws[threadIdx.x] = 0.0f;
    __syncthreads();
    // Detect mask layout: int32 {0,1} has bytes 4k+1..4k+3 == 0; random bool8
    // doesn't. Scan first 4096 slots (16KB; both layouts exceed that).
    int t = threadIdx.x;
    unsigned int found = 0;
#pragma unroll
    for (int k = 0; k < 16; ++k) {
        int slot = t * 16 + k;
        found |= mb[4 * slot + 1] | mb[4 * slot + 2] | mb[4 * slot + 3];
    }
    if (found) atomicOr((int*)(ws + 8), 1);  // 1 => bool8 layout
}

__global__ __launch_bounds__(256) void yolo_main_kernel(
    const float* __restrict__ pred,
    const float* __restrict__ tbox,
    const float* __restrict__ tcls,
    const void* __restrict__ mask,
    float* ws,
    float* __restrict__ out) {
    __shared__ float sbox[TPB * 10];  // 10240 B: per-cell box fields
    __shared__ float sm[TPB];         // 1024 B: per-cell mask as float
    __shared__ float red[4][4];
    const int tid = threadIdx.x;
    const int blk = blockIdx.x;
    const int c = blk * TPB + tid;

    // ---- early coalesced per-cell loads ----
    const float4 tb = ((const float4*)tbox)[c];
    const int mode = ((const int*)(ws + 8))[0];  // uniform
    float mval;
    if (mode) {
        mval = ((const unsigned char*)mask)[c] ? 1.0f : 0.0f;
    } else {
        mval = ((const int*)mask)[c] ? 1.0f : 0.0f;
    }
    sm[tid] = mval;
    __syncthreads();

    // ---- element-parallel pass over pred slab (float2 chunks) ----
    // Block slab: 256 cells x 30 floats = 3840 float2. Chunk idx -> cell
    // idx/15, float2-pos idx%15. pos<5: box fields -> LDS scatter.
    // pos>=5: cls fields -> diff vs tcls (cell cc, float2 index cc*10+(pos-5)).
    float cls_s = 0.0f;
    {
        const float2* gp = (const float2*)(pred + (size_t)blk * (TPB * 30));
        const float2* gc = (const float2*)(tcls + (size_t)blk * (TPB * 20));
#pragma unroll
        for (int j = 0; j < 15; ++j) {
            int idx = tid + TPB * j;   // 0..3839, coalesced
            int cc = idx / 15;         // magic-mul
            int p2 = idx - cc * 15;
            float2 v = gp[idx];
            if (p2 < 5) {
                ((float2*)(sbox + cc * 10))[p2] = v;  // floats cc*10+2*p2 (8B-aligned)
            } else {
                float2 t = gc[cc * 10 + (p2 - 5)];
                float d1 = v.x - t.x, d2 = v.y - t.y;
                cls_s += sm[cc] * (d1 * d1 + d2 * d2);
            }
        }
    }
    __syncthreads();

    // ---- per-cell box computation (cell = tid) ----
    const float* bx = sbox + tid * 10;  // [x0,y0,w0,h0,c0, x1,y1,w1,h1,c1]
    float2 q0 = ((const float2*)bx)[0];
    float2 q1 = ((const float2*)bx)[1];
    float2 q2 = ((const float2*)bx)[2];
    float2 q3 = ((const float2*)bx)[3];
    float2 q4 = ((const float2*)bx)[4];
    float x0 = q0.x, y0 = q0.y, w0 = q1.x, h0 = q1.y, c0 = q2.x;
    float x1 = q2.y, y1 = q3.x, w1 = q3.y, h1 = q4.x, c1 = q4.y;
    float m = mval;

    float noobj_s = (1.0f - m) * (c0 * c0 + c1 * c1);

    float at = (tb.z - tb.x) * (tb.w - tb.y);
    float iou0, iou1;
    {
        float x = x0 * (1.0f / 14.0f), y = y0 * (1.0f / 14.0f);
        float p1x = x - w0 * 0.5f, p1y = y - h0 * 0.5f;
        float p2x = x + w0 * 0.5f, p2y = y + h0 * 0.5f;
        float iw = fmaxf(fminf(p2x, tb.z) - fmaxf(p1x, tb.x), 0.0f);
        float ih = fmaxf(fminf(p2y, tb.w) - fmaxf(p1y, tb.y), 0.0f);
        float inter = iw * ih;
        iou0 = inter / (w0 * h0 + at - inter);
    }
    {
        float x = x1 * (1.0f / 14.0f), y = y1 * (1.0f / 14.0f);
        float p1x = x - w1 * 0.5f, p1y = y - h1 * 0.5f;
        float p2x = x + w1 * 0.5f, p2y = y + h1 * 0.5f;
        float iw = fmaxf(fminf(p2x, tb.z) - fmaxf(p1x, tb.x), 0.0f);
        float ih = fmaxf(fminf(p2y, tb.w) - fmaxf(p1y, tb.y), 0.0f);
        float inter = iw * ih;
        iou1 = inter / (w1 * h1 + at - inter);
    }
    bool sel = iou1 > iou0;  // jnp.argmax: first max wins
    float bxv = sel ? x1 : x0, byv = sel ? y1 : y0;
    float bwv = sel ? w1 : w0, bhv = sel ? h1 : h0;
    float bcv = sel ? c1 : c0;

    float contain_s = m * (bcv - 1.0f) * (bcv - 1.0f);

    float dx = bxv - tb.x, dy = byv - tb.y;
    float dw = sqrtf(bwv) - sqrtf(tb.z);
    float dh = sqrtf(bhv) - sqrtf(tb.w);
    float reg_s = m * (dx * dx + dy * dy + dw * dw + dh * dh);

    // ---- reduction: wave64 shuffle -> LDS -> atomicAdd ----
#pragma unroll
    for (int off = 32; off > 0; off >>= 1) {
        cls_s += __shfl_down(cls_s, off, 64);
        noobj_s += __shfl_down(noobj_s, off, 64);
        contain_s += __shfl_down(contain_s, off, 64);
        reg_s += __shfl_down(reg_s, off, 64);
    }
    int lane = tid & 63;
    int wid = tid >> 6;
    if (lane == 0) {
        red[wid][0] = cls_s;
        red[wid][1] = noobj_s;
        red[wid][2] = contain_s;
        red[wid][3] = reg_s;
    }
    __syncthreads();
    if (tid < 4) {
        float v = red[0][tid] + red[1][tid] + red[2][tid] + red[3][tid];
        atomicAdd(&ws[tid], v);
    }
    __syncthreads();  // all 4 sum-atomics of this block precede the counter

    // ---- last-block finalize (fence + counter, device-scope) ----
    if (tid == 0) {
        __threadfence();
        unsigned int prev = atomicAdd((unsigned int*)(ws + 4), 1u);
        if (prev == (unsigned int)(NBLOCKS - 1)) {
            __threadfence();
            const float inv_n = 1.0f / 4096.0f;
            float cls = atomicAdd(&ws[0], 0.0f) * inv_n;
            float noobj = atomicAdd(&ws[1], 0.0f) * inv_n;
            float contain = atomicAdd(&ws[2], 0.0f) * inv_n;
            float reg = atomicAdd(&ws[3], 0.0f) * inv_n;
            out[0] = cls + 0.5f * noobj + 5.0f * reg + contain;
            out[1] = reg;
            out[2] = contain;
            out[3] = noobj;
            out[4] = cls;
        }
    }
}

extern "C" void kernel_launch(void* const* d_in, const int* in_sizes, int n_in,
                              void* d_out, int out_size, void* d_ws,
                              size_t ws_size, hipStream_t stream) {
    const float* pred = (const float*)d_in[0];
    const float* tbox = (const float*)d_in[1];
    const float* tcls = (const float*)d_in[2];
    const void* mask = d_in[3];
    float* ws = (float*)d_ws;
    float* out = (float*)d_out;

    yolo_init_kernel<<<1, 256, 0, stream>>>(ws, (const unsigned char*)mask);
    yolo_main_kernel<<<NBLOCKS, TPB, 0, stream>>>(pred, tbox, tcls, mask, ws,
                                                  out);
}

// Round 5
// 210.564 us; speedup vs baseline: 1.4577x; 1.4577x over previous
//
#include <hip/hip_runtime.h>

// YOLO loss: N=4096, S=14, B=2, NCLS=20. Cells = 802816.
// R5: kill same-cache-line atomic contention. R1/R4 evidence: R1's L3-warm
// replays flat at 68us (fixed serialization, not BW); R4's +3136 returning
// counter-atomics on the SAME line (with a trailing __syncthreads pinning each
// block until its atomic completed) scaled it to 163us. 12-16k cross-XCD RMWs
// on one line @ ~5-10ns each == the whole kernel time.
//  -> each block plain-stores 4 partials to a private slot (no contention),
//     tiny 3rd dispatch reduces 3136x4 floats.
// Also: batch ALL global loads up front in branchless unrolled loops (R4's
// branchy loop emitted per-iteration vmcnt waits, VGPR=20). tcls loaded with
// clamped addresses (5 redundant L2-hit loads/thread, zero extra HBM).
// LDS ~11.4KB, ~90 VGPR -> ~5-6 waves/SIMD.

#define NCELLS (4096 * 14 * 14)
#define TPB 256
#define NBLOCKS (NCELLS / TPB)  // 3136, exact

// ws layout (floats): [8] mask-mode flag (int); [16 + 4*blk .. +3] per-block
// partials (cls, noobj, contain, reg). Total 16 + 12544 floats ~= 50 KB.

__global__ void yolo_init_kernel(float* ws, const unsigned char* mb) {
    if (threadIdx.x == 0) ((int*)ws)[8] = 0;
    __syncthreads();
    // Detect mask layout: int32 {0,1} has bytes 4k+1..4k+3 == 0; random bool8
    // doesn't. Scan first 4096 slots (16KB; both layouts exceed that).
    int t = threadIdx.x;
    unsigned int found = 0;
#pragma unroll
    for (int k = 0; k < 16; ++k) {
        int slot = t * 16 + k;
        found |= mb[4 * slot + 1] | mb[4 * slot + 2] | mb[4 * slot + 3];
    }
    if (found) atomicOr((int*)ws + 8, 1);  // 1 => bool8 layout
}

__global__ __launch_bounds__(256) void yolo_main_kernel(
    const float* __restrict__ pred,
    const float* __restrict__ tbox,
    const float* __restrict__ tcls,
    const void* __restrict__ mask,
    float* __restrict__ ws) {
    __shared__ float sbox[TPB * 10];  // 10240 B: per-cell box fields
    __shared__ float sm[TPB];         // 1024 B: per-cell mask as float
    __shared__ float red[4][4];
    const int tid = threadIdx.x;
    const int blk = blockIdx.x;
    const int c = blk * TPB + tid;

    // ---- issue ALL global loads up front (branchless -> one vmcnt batch) ----
    const float2* gp = (const float2*)(pred + (size_t)blk * (TPB * 30));
    const float2* gc = (const float2*)(tcls + (size_t)blk * (TPB * 20));
    float2 pv[15];
#pragma unroll
    for (int j = 0; j < 15; ++j) pv[j] = gp[tid + TPB * j];
    float2 tv[15];
#pragma unroll
    for (int j = 0; j < 15; ++j) {
        int idx = tid + TPB * j;
        int cc = idx / 15;           // magic-mul
        int p2 = idx - cc * 15;      // == (tid + j) % 15
        int gi = cc * 10 + (p2 >= 5 ? p2 - 5 : 0);  // clamped (dummy if box)
        tv[j] = gc[gi];
    }
    const float4 tb = ((const float4*)tbox)[c];
    const int mode = ((const int*)ws)[8];  // uniform
    float mval;
    if (mode) {
        mval = ((const unsigned char*)mask)[c] ? 1.0f : 0.0f;
    } else {
        mval = ((const int*)mask)[c] ? 1.0f : 0.0f;
    }
    sm[tid] = mval;
    __syncthreads();

    // ---- element-parallel: box chunks -> LDS scatter, cls chunks -> diff ----
    float cls_s = 0.0f;
#pragma unroll
    for (int j = 0; j < 15; ++j) {
        int idx = tid + TPB * j;
        int cc = idx / 15;
        int p2 = idx - cc * 15;
        if (p2 < 5) {
            ((float2*)(sbox + cc * 10))[p2] = pv[j];
        } else {
            float d1 = pv[j].x - tv[j].x, d2 = pv[j].y - tv[j].y;
            cls_s += sm[cc] * (d1 * d1 + d2 * d2);
        }
    }
    __syncthreads();

    // ---- per-cell box computation (cell = tid) ----
    const float* bx = sbox + tid * 10;  // [x0,y0,w0,h0,c0, x1,y1,w1,h1,c1]
    float2 q0 = ((const float2*)bx)[0];
    float2 q1 = ((const float2*)bx)[1];
    float2 q2 = ((const float2*)bx)[2];
    float2 q3 = ((const float2*)bx)[3];
    float2 q4 = ((const float2*)bx)[4];
    float x0 = q0.x, y0 = q0.y, w0 = q1.x, h0 = q1.y, c0 = q2.x;
    float x1 = q2.y, y1 = q3.x, w1 = q3.y, h1 = q4.x, c1 = q4.y;
    float m = mval;

    float noobj_s = (1.0f - m) * (c0 * c0 + c1 * c1);

    float at = (tb.z - tb.x) * (tb.w - tb.y);
    float iou0, iou1;
    {
        float x = x0 * (1.0f / 14.0f), y = y0 * (1.0f / 14.0f);
        float iw = fmaxf(fminf(x + w0 * 0.5f, tb.z) - fmaxf(x - w0 * 0.5f, tb.x), 0.0f);
        float ih = fmaxf(fminf(y + h0 * 0.5f, tb.w) - fmaxf(y - h0 * 0.5f, tb.y), 0.0f);
        float inter = iw * ih;
        iou0 = inter / (w0 * h0 + at - inter);
    }
    {
        float x = x1 * (1.0f / 14.0f), y = y1 * (1.0f / 14.0f);
        float iw = fmaxf(fminf(x + w1 * 0.5f, tb.z) - fmaxf(x - w1 * 0.5f, tb.x), 0.0f);
        float ih = fmaxf(fminf(y + h1 * 0.5f, tb.w) - fmaxf(y - h1 * 0.5f, tb.y), 0.0f);
        float inter = iw * ih;
        iou1 = inter / (w1 * h1 + at - inter);
    }
    bool sel = iou1 > iou0;  // jnp.argmax: first max wins
    float bxv = sel ? x1 : x0, byv = sel ? y1 : y0;
    float bwv = sel ? w1 : w0, bhv = sel ? h1 : h0;
    float bcv = sel ? c1 : c0;

    float contain_s = m * (bcv - 1.0f) * (bcv - 1.0f);

    float dx = bxv - tb.x, dy = byv - tb.y;
    float dw = sqrtf(bwv) - sqrtf(tb.z);
    float dh = sqrtf(bhv) - sqrtf(tb.w);
    float reg_s = m * (dx * dx + dy * dy + dw * dw + dh * dh);

    // ---- reduction: wave64 shuffle -> LDS -> private partial slot ----
#pragma unroll
    for (int off = 32; off > 0; off >>= 1) {
        cls_s += __shfl_down(cls_s, off, 64);
        noobj_s += __shfl_down(noobj_s, off, 64);
        contain_s += __shfl_down(contain_s, off, 64);
        reg_s += __shfl_down(reg_s, off, 64);
    }
    int lane = tid & 63;
    int wid = tid >> 6;
    if (lane == 0) {
        red[wid][0] = cls_s;
        red[wid][1] = noobj_s;
        red[wid][2] = contain_s;
        red[wid][3] = reg_s;
    }
    __syncthreads();
    if (tid < 4) {
        float v = red[0][tid] + red[1][tid] + red[2][tid] + red[3][tid];
        ws[16 + 4 * blk + tid] = v;  // plain store, zero contention
    }
}

__global__ __launch_bounds__(256) void yolo_reduce_kernel(
    const float* __restrict__ ws, float* __restrict__ out) {
    const float4* part = (const float4*)(ws + 16);  // one float4 per block
    float s0 = 0.0f, s1 = 0.0f, s2 = 0.0f, s3 = 0.0f;
    for (int i = threadIdx.x; i < NBLOCKS; i += 256) {
        float4 p = part[i];
        s0 += p.x; s1 += p.y; s2 += p.z; s3 += p.w;
    }
#pragma unroll
    for (int off = 32; off > 0; off >>= 1) {
        s0 += __shfl_down(s0, off, 64);
        s1 += __shfl_down(s1, off, 64);
        s2 += __shfl_down(s2, off, 64);
        s3 += __shfl_down(s3, off, 64);
    }
    __shared__ float red[4][4];
    int lane = threadIdx.x & 63;
    int wid = threadIdx.x >> 6;
    if (lane == 0) {
        red[wid][0] = s0;
        red[wid][1] = s1;
        red[wid][2] = s2;
        red[wid][3] = s3;
    }
    __syncthreads();
    if (threadIdx.x == 0) {
        const float inv_n = 1.0f / 4096.0f;
        float cls = (red[0][0] + red[1][0] + red[2][0] + red[3][0]) * inv_n;
        float noobj = (red[0][1] + red[1][1] + red[2][1] + red[3][1]) * inv_n;
        float contain = (red[0][2] + red[1][2] + red[2][2] + red[3][2]) * inv_n;
        float reg = (red[0][3] + red[1][3] + red[2][3] + red[3][3]) * inv_n;
        out[0] = cls + 0.5f * noobj + 5.0f * reg + contain;
        out[1] = reg;
        out[2] = contain;
        out[3] = noobj;
        out[4] = cls;
    }
}

extern "C" void kernel_launch(void* const* d_in, const int* in_sizes, int n_in,
                              void* d_out, int out_size, void* d_ws,
                              size_t ws_size, hipStream_t stream) {
    const float* pred = (const float*)d_in[0];
    const float* tbox = (const float*)d_in[1];
    const float* tcls = (const float*)d_in[2];
    const void* mask = d_in[3];
    float* ws = (float*)d_ws;
    float* out = (float*)d_out;

    yolo_init_kernel<<<1, 256, 0, stream>>>(ws, (const unsigned char*)mask);
    yolo_main_kernel<<<NBLOCKS, TPB, 0, stream>>>(pred, tbox, tcls, mask, ws);
    yolo_reduce_kernel<<<1, 256, 0, stream>>>(ws, out);
}